// Round 5
// baseline (105.694 us; speedup 1.0000x reference)
//
#include <hip/hip_runtime.h>
#include <math.h>

// Problem constants (from reference)
#define BB 4
#define LL 4096
#define DD 2048
#define NN 8

// Chunked-scan parameters
#define LC 64               // chunk length
#define CC (LL / LC)        // 64 chunks
#define WW 64               // warmup steps: p^64 <= ~5e-11 truncation
#define G  8                // l-steps per pipeline group
#define DP (DD / 2)         // 1024 channel-pairs

typedef float f32x2 __attribute__((ext_vector_type(2)));

// Two channels per thread (8B/lane). Depth-2 ping-pong pipeline: while group
// A computes, group B's 8 loads are in flight; A refills right after its
// compute. No register copies -> no full vmcnt drain per group (R4 lesson).
__global__ __launch_bounds__(256, 4) void ema_scan_kernel(
    const float* __restrict__ x,      // (B, L, D)
    const float* __restrict__ delta,  // (D, N, 1)
    const float* __restrict__ gamma,  // (D, N, 1)
    float* __restrict__ y)            // (B, L, D)
{
    const int t = blockIdx.x * blockDim.x + threadIdx.x;
    const int dp = t & (DP - 1);         // channel-pair index (lane -> contiguous)
    const int rest = t >> 10;            // log2(DP) = 10
    const int c = rest & (CC - 1);       // chunk (uniform within a block)
    const int b = rest >> 6;             // log2(CC) = 6
    const int d0 = dp * 2;

    const float scale = 0.022097086912079608f;  // 1/sqrt(2048)

    float p0[NN], g0[NN], s0[NN], p1[NN], g1[NN], s1[NN];
#pragma unroll
    for (int n = 0; n < NN; ++n) {
        const float dl0 = delta[(size_t)d0 * NN + n];
        const float dl1 = delta[(size_t)(d0 + 1) * NN + n];
        p0[n] = 1.0f / (1.0f + expf(-dl0));
        p1[n] = 1.0f / (1.0f + expf(-dl1));
        g0[n] = gamma[(size_t)d0 * NN + n] * scale;
        g1[n] = gamma[(size_t)(d0 + 1) * NN + n] * scale;
        s0[n] = 0.0f;
        s1[n] = 0.0f;
    }

    const int l0 = c * LC;
    const int nwarm = (c > 0) ? WW : 0;          // uniform per block (0 or 64)
    const f32x2* xp = (const f32x2*)(x + ((size_t)b * LL + (size_t)(l0 - nwarm)) * DD) + dp;
    f32x2* yp = (f32x2*)(y + ((size_t)b * LL + (size_t)l0) * DD) + dp;
    const int total = nwarm + LC;                // 64 or 128 (both % 16 == 0)

    f32x2 A[G], B[G];
#pragma unroll
    for (int u = 0; u < G; ++u) A[u] = xp[(size_t)u * DP];
#pragma unroll
    for (int u = 0; u < G; ++u) B[u] = xp[(size_t)(G + u) * DP];

    for (int base = 0; base < total; base += 2 * G) {
        // ---- group A: l-steps [base, base+G)
        if (base >= nwarm) {
            const int lo = base - nwarm;
#pragma unroll
            for (int u = 0; u < G; ++u) {
                float ox = 0.0f, oy = 0.0f;
#pragma unroll
                for (int n = 0; n < NN; ++n) {
                    s0[n] = fmaf(p0[n], s0[n], A[u].x);
                    ox = fmaf(g0[n], s0[n], ox);
                    s1[n] = fmaf(p1[n], s1[n], A[u].y);
                    oy = fmaf(g1[n], s1[n], oy);
                }
                f32x2 o; o.x = ox; o.y = oy;
                __builtin_nontemporal_store(o, &yp[(size_t)(lo + u) * DP]);
            }
        } else {
#pragma unroll
            for (int u = 0; u < G; ++u) {
#pragma unroll
                for (int n = 0; n < NN; ++n) {
                    s0[n] = fmaf(p0[n], s0[n], A[u].x);
                    s1[n] = fmaf(p1[n], s1[n], A[u].y);
                }
            }
        }
        if (base + 2 * G < total) {              // refill A with group base+2G
#pragma unroll
            for (int u = 0; u < G; ++u) A[u] = xp[(size_t)(base + 2 * G + u) * DP];
        }

        // ---- group B: l-steps [base+G, base+2G)
        const int baseB = base + G;
        if (baseB >= nwarm) {
            const int lo = baseB - nwarm;
#pragma unroll
            for (int u = 0; u < G; ++u) {
                float ox = 0.0f, oy = 0.0f;
#pragma unroll
                for (int n = 0; n < NN; ++n) {
                    s0[n] = fmaf(p0[n], s0[n], B[u].x);
                    ox = fmaf(g0[n], s0[n], ox);
                    s1[n] = fmaf(p1[n], s1[n], B[u].y);
                    oy = fmaf(g1[n], s1[n], oy);
                }
                f32x2 o; o.x = ox; o.y = oy;
                __builtin_nontemporal_store(o, &yp[(size_t)(lo + u) * DP]);
            }
        } else {
#pragma unroll
            for (int u = 0; u < G; ++u) {
#pragma unroll
                for (int n = 0; n < NN; ++n) {
                    s0[n] = fmaf(p0[n], s0[n], B[u].x);
                    s1[n] = fmaf(p1[n], s1[n], B[u].y);
                }
            }
        }
        if (base + 3 * G < total) {              // refill B with group base+3G
#pragma unroll
            for (int u = 0; u < G; ++u) B[u] = xp[(size_t)(base + 3 * G + u) * DP];
        }
    }
}

extern "C" void kernel_launch(void* const* d_in, const int* in_sizes, int n_in,
                              void* d_out, int out_size, void* d_ws, size_t ws_size,
                              hipStream_t stream) {
    const float* x     = (const float*)d_in[0];  // (B, L, D) fp32
    const float* delta = (const float*)d_in[1];  // (D, N, 1) fp32
    const float* gamma = (const float*)d_in[2];  // (D, N, 1) fp32
    float* y = (float*)d_out;                    // (B, L, D) fp32

    const int total_threads = BB * CC * DP;      // 262144
    const int block = 256;
    const int grid = total_threads / block;      // 1024 blocks
    ema_scan_kernel<<<grid, block, 0, stream>>>(x, delta, gamma, y);
}

// Round 6
// 69.434 us; speedup vs baseline: 1.5222x; 1.5222x over previous
//
#include <hip/hip_runtime.h>
#include <math.h>

// Problem constants (from reference)
#define BB 4
#define LL 4096
#define DD 2048
#define NN 8

// Chunked-scan parameters
#define LC 64               // chunk length
#define CC (LL / LC)        // 64 chunks
#define WW 64               // warmup steps: p^64 <= ~5e-11 truncation
#define G  8                // l-steps per pipeline group
#define DP (DD / 2)         // 1024 channel-pairs

typedef float f32x2 __attribute__((ext_vector_type(2)));

// Two channels per thread (8B/lane). Depth-2 ping-pong pipeline.
// R5 lesson: under __launch_bounds__(256,4) the allocator pinned VGPR=64 and
// spilled the second buffer to scratch (WRITE_SIZE 131->255 MB). Open the
// budget with (256,2): ~100 VGPRs needed, stays within the <=128 step so
// occupancy remains 4 waves/SIMD and the 1024-block grid is fully resident.
__global__ __launch_bounds__(256, 2) void ema_scan_kernel(
    const float* __restrict__ x,      // (B, L, D)
    const float* __restrict__ delta,  // (D, N, 1)
    const float* __restrict__ gamma,  // (D, N, 1)
    float* __restrict__ y)            // (B, L, D)
{
    const int t = blockIdx.x * blockDim.x + threadIdx.x;
    const int dp = t & (DP - 1);         // channel-pair index (lane -> contiguous)
    const int rest = t >> 10;            // log2(DP) = 10
    const int c = rest & (CC - 1);       // chunk (uniform within a block)
    const int b = rest >> 6;             // log2(CC) = 6
    const int d0 = dp * 2;

    const float scale = 0.022097086912079608f;  // 1/sqrt(2048)

    float p0[NN], g0[NN], s0[NN], p1[NN], g1[NN], s1[NN];
#pragma unroll
    for (int n = 0; n < NN; ++n) {
        const float dl0 = delta[(size_t)d0 * NN + n];
        const float dl1 = delta[(size_t)(d0 + 1) * NN + n];
        p0[n] = 1.0f / (1.0f + expf(-dl0));
        p1[n] = 1.0f / (1.0f + expf(-dl1));
        g0[n] = gamma[(size_t)d0 * NN + n] * scale;
        g1[n] = gamma[(size_t)(d0 + 1) * NN + n] * scale;
        s0[n] = 0.0f;
        s1[n] = 0.0f;
    }

    const int l0 = c * LC;
    const int nwarm = (c > 0) ? WW : 0;          // uniform per block (0 or 64)
    const f32x2* xp = (const f32x2*)(x + ((size_t)b * LL + (size_t)(l0 - nwarm)) * DD) + dp;
    f32x2* yp = (f32x2*)(y + ((size_t)b * LL + (size_t)l0) * DD) + dp;
    const int total = nwarm + LC;                // 64 or 128 (both % 16 == 0)

    f32x2 A[G], B[G];
#pragma unroll
    for (int u = 0; u < G; ++u) A[u] = xp[(size_t)u * DP];
#pragma unroll
    for (int u = 0; u < G; ++u) B[u] = xp[(size_t)(G + u) * DP];

    for (int base = 0; base < total; base += 2 * G) {
        // ---- group A: l-steps [base, base+G)
        if (base >= nwarm) {
            const int lo = base - nwarm;
#pragma unroll
            for (int u = 0; u < G; ++u) {
                float ox = 0.0f, oy = 0.0f;
#pragma unroll
                for (int n = 0; n < NN; ++n) {
                    s0[n] = fmaf(p0[n], s0[n], A[u].x);
                    ox = fmaf(g0[n], s0[n], ox);
                    s1[n] = fmaf(p1[n], s1[n], A[u].y);
                    oy = fmaf(g1[n], s1[n], oy);
                }
                f32x2 o; o.x = ox; o.y = oy;
                __builtin_nontemporal_store(o, &yp[(size_t)(lo + u) * DP]);
            }
        } else {
#pragma unroll
            for (int u = 0; u < G; ++u) {
#pragma unroll
                for (int n = 0; n < NN; ++n) {
                    s0[n] = fmaf(p0[n], s0[n], A[u].x);
                    s1[n] = fmaf(p1[n], s1[n], A[u].y);
                }
            }
        }
        if (base + 2 * G < total) {              // refill A with group base+2G
#pragma unroll
            for (int u = 0; u < G; ++u) A[u] = xp[(size_t)(base + 2 * G + u) * DP];
        }

        // ---- group B: l-steps [base+G, base+2G)
        const int baseB = base + G;
        if (baseB >= nwarm) {
            const int lo = baseB - nwarm;
#pragma unroll
            for (int u = 0; u < G; ++u) {
                float ox = 0.0f, oy = 0.0f;
#pragma unroll
                for (int n = 0; n < NN; ++n) {
                    s0[n] = fmaf(p0[n], s0[n], B[u].x);
                    ox = fmaf(g0[n], s0[n], ox);
                    s1[n] = fmaf(p1[n], s1[n], B[u].y);
                    oy = fmaf(g1[n], s1[n], oy);
                }
                f32x2 o; o.x = ox; o.y = oy;
                __builtin_nontemporal_store(o, &yp[(size_t)(lo + u) * DP]);
            }
        } else {
#pragma unroll
            for (int u = 0; u < G; ++u) {
#pragma unroll
                for (int n = 0; n < NN; ++n) {
                    s0[n] = fmaf(p0[n], s0[n], B[u].x);
                    s1[n] = fmaf(p1[n], s1[n], B[u].y);
                }
            }
        }
        if (base + 3 * G < total) {              // refill B with group base+3G
#pragma unroll
            for (int u = 0; u < G; ++u) B[u] = xp[(size_t)(base + 3 * G + u) * DP];
        }
    }
}

extern "C" void kernel_launch(void* const* d_in, const int* in_sizes, int n_in,
                              void* d_out, int out_size, void* d_ws, size_t ws_size,
                              hipStream_t stream) {
    const float* x     = (const float*)d_in[0];  // (B, L, D) fp32
    const float* delta = (const float*)d_in[1];  // (D, N, 1) fp32
    const float* gamma = (const float*)d_in[2];  // (D, N, 1) fp32
    float* y = (float*)d_out;                    // (B, L, D) fp32

    const int total_threads = BB * CC * DP;      // 262144
    const int block = 256;
    const int grid = total_threads / block;      // 1024 blocks
    ema_scan_kernel<<<grid, block, 0, stream>>>(x, delta, gamma, y);
}

// Round 7
// 56.935 us; speedup vs baseline: 1.8564x; 1.2195x over previous
//
#include <hip/hip_runtime.h>
#include <math.h>

// Problem constants (from reference)
#define BB 4
#define LL 4096
#define DD 2048
#define NN 8

// Chunked-scan parameters
#define LC 64               // chunk length
#define CC (LL / LC)        // 64 chunks
#define WW 32               // warmup steps: p^32 <= ~1.5e-5 -> y-error ~1e-4 << 1.96e-2
#define G  8                // l-steps per pipeline group
#define DP (DD / 2)         // 1024 channel-pairs

typedef float f32x2 __attribute__((ext_vector_type(2)));

// Two channels per thread (8B/lane). Depth-1 prefetch (R4 structure: proven
// spill-free at VGPR=64). R6 lesson: depth-2 ping-pong adds nothing once
// spills are gone -- the binding constraint is logical memory traffic
// (~5.8 TB/s path incl. L3-served warmup reads), so shrink warmup instead.
__global__ __launch_bounds__(256, 4) void ema_scan_kernel(
    const float* __restrict__ x,      // (B, L, D)
    const float* __restrict__ delta,  // (D, N, 1)
    const float* __restrict__ gamma,  // (D, N, 1)
    float* __restrict__ y)            // (B, L, D)
{
    const int t = blockIdx.x * blockDim.x + threadIdx.x;
    const int dp = t & (DP - 1);         // channel-pair index (lane -> contiguous)
    const int rest = t >> 10;            // log2(DP) = 10
    const int c = rest & (CC - 1);       // chunk (uniform within a block)
    const int b = rest >> 6;             // log2(CC) = 6
    const int d0 = dp * 2;

    const float scale = 0.022097086912079608f;  // 1/sqrt(2048)

    float p0[NN], g0[NN], s0[NN], p1[NN], g1[NN], s1[NN];
#pragma unroll
    for (int n = 0; n < NN; ++n) {
        const float dl0 = delta[(size_t)d0 * NN + n];
        const float dl1 = delta[(size_t)(d0 + 1) * NN + n];
        p0[n] = 1.0f / (1.0f + expf(-dl0));
        p1[n] = 1.0f / (1.0f + expf(-dl1));
        g0[n] = gamma[(size_t)d0 * NN + n] * scale;
        g1[n] = gamma[(size_t)(d0 + 1) * NN + n] * scale;
        s0[n] = 0.0f;
        s1[n] = 0.0f;
    }

    const int l0 = c * LC;
    const int nwarm = (c > 0) ? WW : 0;          // uniform per block (0 or 32)
    const f32x2* xp = (const f32x2*)(x + ((size_t)b * LL + (size_t)(l0 - nwarm)) * DD) + dp;
    f32x2* yp = (f32x2*)(y + ((size_t)b * LL + (size_t)l0) * DD) + dp;
    const int total = nwarm + LC;                // 64 or 96 (both % 8 == 0)

    // Software-pipelined groups of G: issue next group's loads before the
    // serial FMA chains of the current group run.
    f32x2 cur[G];
#pragma unroll
    for (int u = 0; u < G; ++u) cur[u] = xp[(size_t)u * DP];

    for (int base = 0; base < total; base += G) {
        f32x2 nxt[G];
        const bool more = (base + G) < total;    // uniform
        if (more) {
#pragma unroll
            for (int u = 0; u < G; ++u) nxt[u] = xp[(size_t)(base + G + u) * DP];
        }
        if (base >= nwarm) {
            // main region: scan + output (nontemporal stores: y never re-read)
            const int lo = base - nwarm;
#pragma unroll
            for (int u = 0; u < G; ++u) {
                float ox = 0.0f, oy = 0.0f;
#pragma unroll
                for (int n = 0; n < NN; ++n) {
                    s0[n] = fmaf(p0[n], s0[n], cur[u].x);
                    ox = fmaf(g0[n], s0[n], ox);
                    s1[n] = fmaf(p1[n], s1[n], cur[u].y);
                    oy = fmaf(g1[n], s1[n], oy);
                }
                f32x2 o; o.x = ox; o.y = oy;
                __builtin_nontemporal_store(o, &yp[(size_t)(lo + u) * DP]);
            }
        } else {
            // warmup region: state update only
#pragma unroll
            for (int u = 0; u < G; ++u) {
#pragma unroll
                for (int n = 0; n < NN; ++n) {
                    s0[n] = fmaf(p0[n], s0[n], cur[u].x);
                    s1[n] = fmaf(p1[n], s1[n], cur[u].y);
                }
            }
        }
#pragma unroll
        for (int u = 0; u < G; ++u) cur[u] = nxt[u];
    }
}

extern "C" void kernel_launch(void* const* d_in, const int* in_sizes, int n_in,
                              void* d_out, int out_size, void* d_ws, size_t ws_size,
                              hipStream_t stream) {
    const float* x     = (const float*)d_in[0];  // (B, L, D) fp32
    const float* delta = (const float*)d_in[1];  // (D, N, 1) fp32
    const float* gamma = (const float*)d_in[2];  // (D, N, 1) fp32
    float* y = (float*)d_out;                    // (B, L, D) fp32

    const int total_threads = BB * CC * DP;      // 262144
    const int block = 256;
    const int grid = total_threads / block;      // 1024 blocks
    ema_scan_kernel<<<grid, block, 0, stream>>>(x, delta, gamma, y);
}